// Round 2
// baseline (741.597 us; speedup 1.0000x reference)
//
#include <hip/hip_runtime.h>
#include <math.h>

#define B_SZ      1024
#define INPUT_DIM 1024
#define D_MODEL   1024
#define NHEAD     16
#define D_HEAD    64
#define D_IN      2048      // INPUT_DIM + D_MODEL
#define N_QKV     3072

// ---------------------------------------------------------------------------
// Kernel 1: qkv = concat(x,h) @ Wqkv + bias        (1024 x 2048 x 3072, fp32)
// BM=64, BN=128, BK=16, 256 threads, TM=4, TN=8 -> grid (24, 16) = 384 blocks
// ---------------------------------------------------------------------------
__global__ __launch_bounds__(256) void gemm_qkv_kernel(
    const float* __restrict__ x, const float* __restrict__ h,
    const float* __restrict__ W, const float* __restrict__ bias,
    float* __restrict__ out)
{
    __shared__ float As[16][68];    // [k][m], +4 pad (keeps 16B align, spreads banks)
    __shared__ float Bs[16][132];   // [k][n], +4 pad

    const int tid = threadIdx.x;
    const int ty  = tid >> 4;       // 0..15 -> owns rows m0 + ty*4 ..
    const int tx  = tid & 15;       // 0..15 -> owns cols n0 + tx*8 ..
    const int m0  = blockIdx.y * 64;
    const int n0  = blockIdx.x * 128;

    // staging indices
    const int arow = tid >> 2;          // 0..63
    const int acol = (tid & 3) * 4;     // 0,4,8,12
    const int brow = tid >> 5;          // 0..7  (second load: +8)
    const int bcol = (tid & 31) * 4;    // 0..124

    float c[4][8];
#pragma unroll
    for (int i = 0; i < 4; ++i)
#pragma unroll
        for (int j = 0; j < 8; ++j) c[i][j] = 0.f;

    for (int kt = 0; kt < D_IN; kt += 16) {
        // global -> regs
        const int colA = kt + acol;
        const float* asrc = (colA < INPUT_DIM)
            ? (x + (size_t)(m0 + arow) * INPUT_DIM + colA)
            : (h + (size_t)(m0 + arow) * D_MODEL  + (colA - INPUT_DIM));
        float4 av  = *reinterpret_cast<const float4*>(asrc);
        float4 bv0 = *reinterpret_cast<const float4*>(W + (size_t)(kt + brow    ) * N_QKV + n0 + bcol);
        float4 bv1 = *reinterpret_cast<const float4*>(W + (size_t)(kt + brow + 8) * N_QKV + n0 + bcol);

        __syncthreads();   // previous tile fully consumed
        As[acol + 0][arow] = av.x;
        As[acol + 1][arow] = av.y;
        As[acol + 2][arow] = av.z;
        As[acol + 3][arow] = av.w;
        *reinterpret_cast<float4*>(&Bs[brow    ][bcol]) = bv0;
        *reinterpret_cast<float4*>(&Bs[brow + 8][bcol]) = bv1;
        __syncthreads();

#pragma unroll
        for (int k = 0; k < 16; ++k) {
            float4 a  = *reinterpret_cast<const float4*>(&As[k][ty * 4]);
            float4 b0 = *reinterpret_cast<const float4*>(&Bs[k][tx * 8]);
            float4 b1 = *reinterpret_cast<const float4*>(&Bs[k][tx * 8 + 4]);
            float avv[4] = {a.x, a.y, a.z, a.w};
            float bvv[8] = {b0.x, b0.y, b0.z, b0.w, b1.x, b1.y, b1.z, b1.w};
#pragma unroll
            for (int i = 0; i < 4; ++i)
#pragma unroll
                for (int j = 0; j < 8; ++j)
                    c[i][j] = fmaf(avv[i], bvv[j], c[i][j]);
        }
    }

    // epilogue: + bias, store
    float bvals[8];
#pragma unroll
    for (int j = 0; j < 8; ++j) bvals[j] = bias[n0 + tx * 8 + j];
#pragma unroll
    for (int i = 0; i < 4; ++i) {
        const int row = m0 + ty * 4 + i;
        float* dst = out + (size_t)row * N_QKV + n0 + tx * 8;
        float4 o0, o1;
        o0.x = c[i][0] + bvals[0]; o0.y = c[i][1] + bvals[1];
        o0.z = c[i][2] + bvals[2]; o0.w = c[i][3] + bvals[3];
        o1.x = c[i][4] + bvals[4]; o1.y = c[i][5] + bvals[5];
        o1.z = c[i][6] + bvals[6]; o1.w = c[i][7] + bvals[7];
        *reinterpret_cast<float4*>(dst)     = o0;
        *reinterpret_cast<float4*>(dst + 4) = o1;
    }
}

// ---------------------------------------------------------------------------
// Kernel 2: w = sigmoid(xh @ Ww + bw), r = sigmoid(xh @ Wr + br)
// one block per batch row, 256 threads: 8 K-slices x 32 outputs (16 w, 16 r)
// ---------------------------------------------------------------------------
__global__ __launch_bounds__(256) void gemm_wr_kernel(
    const float* __restrict__ x, const float* __restrict__ h,
    const float* __restrict__ Ww, const float* __restrict__ Wwb,
    const float* __restrict__ Wr, const float* __restrict__ Wrb,
    float* __restrict__ w_out, float* __restrict__ r_out)
{
    const int b     = blockIdx.x;
    const int tid   = threadIdx.x;
    const int j     = tid & 31;      // 0..15 -> w col, 16..31 -> r col
    const int slice = tid >> 5;      // 0..7, each covers 256 k's
    const int col   = j & 15;
    const float* Wm = (j < 16) ? Ww : Wr;

    const int k0 = slice * 256;
    const float* src = (k0 < INPUT_DIM) ? (x + (size_t)b * INPUT_DIM + k0)
                                        : (h + (size_t)b * D_MODEL + (k0 - INPUT_DIM));
    float acc = 0.f;
#pragma unroll 8
    for (int i = 0; i < 256; ++i)
        acc = fmaf(src[i], Wm[(size_t)(k0 + i) * NHEAD + col], acc);

    __shared__ float red[8][32];
    red[slice][j] = acc;
    __syncthreads();
    if (tid < 32) {
        float s = 0.f;
#pragma unroll
        for (int i = 0; i < 8; ++i) s += red[i][tid];
        const int cc = tid & 15;
        if (tid < 16) {
            s += Wwb[cc];
            w_out[(size_t)b * NHEAD + cc] = 1.f / (1.f + expf(-s));
        } else {
            s += Wrb[cc];
            r_out[(size_t)b * NHEAD + cc] = 1.f / (1.f + expf(-s));
        }
    }
}

// ---------------------------------------------------------------------------
// Kernel 3: AM update. One wave per (b, n). lane = v index (0..63).
// AM row (64 floats) held in 16x float4 registers.
//   q,k unitnorm -> v_r = AM@k -> vp = w*(v - v_r) -> AM_new = AM + vp⊗k
//   h_new = (AM_new @ q) * r
// ---------------------------------------------------------------------------
__global__ __launch_bounds__(64) void am_update_kernel(
    const float* __restrict__ qkv, const float* __restrict__ AM,
    const float* __restrict__ w_arr, const float* __restrict__ r_arr,
    float* __restrict__ h_out, float* __restrict__ am_out)
{
    const int bn   = blockIdx.x;      // b*16 + n
    const int b    = bn >> 4;
    const int n    = bn & 15;
    const int lane = threadIdx.x;     // 0..63 = v index

    const float* row = qkv + (size_t)b * N_QKV;
    float qv = row[             n * 64 + lane];
    float kv = row[D_MODEL    + n * 64 + lane];
    float vv = row[2 * D_MODEL + n * 64 + lane];

    // wave-64 sum of squares for q and k
    float qs = qv * qv, ks = kv * kv;
#pragma unroll
    for (int off = 32; off > 0; off >>= 1) {
        qs += __shfl_xor(qs, off);
        ks += __shfl_xor(ks, off);
    }
    const float qn = qv / fmaxf(sqrtf(qs), 1e-12f);
    const float kn = kv / fmaxf(sqrtf(ks), 1e-12f);

    __shared__ float qL[64], kL[64];
    qL[lane] = qn;
    kL[lane] = kn;
    __syncthreads();

    // load AM row (v = lane): 64 contiguous floats
    const float4* amr = reinterpret_cast<const float4*>(AM + (size_t)bn * 4096 + lane * 64);
    float4 am[16];
#pragma unroll
    for (int i = 0; i < 16; ++i) am[i] = amr[i];

    // v_r[lane] = sum_q AM[lane][q] * k[q]
    float vr = 0.f;
#pragma unroll
    for (int i = 0; i < 16; ++i) {
        float4 kk = *reinterpret_cast<const float4*>(&kL[i * 4]);
        vr = fmaf(am[i].x, kk.x, vr);
        vr = fmaf(am[i].y, kk.y, vr);
        vr = fmaf(am[i].z, kk.z, vr);
        vr = fmaf(am[i].w, kk.w, vr);
    }

    const float wv = w_arr[bn];
    const float rv = r_arr[bn];
    const float vp = wv * (vv - vr);

    // AM_new row + h accumulation
    float hv = 0.f;
    float4* amo = reinterpret_cast<float4*>(am_out + (size_t)bn * 4096 + lane * 64);
#pragma unroll
    for (int i = 0; i < 16; ++i) {
        float4 kk = *reinterpret_cast<const float4*>(&kL[i * 4]);
        float4 qq = *reinterpret_cast<const float4*>(&qL[i * 4]);
        float4 a  = am[i];
        a.x = fmaf(vp, kk.x, a.x);
        a.y = fmaf(vp, kk.y, a.y);
        a.z = fmaf(vp, kk.z, a.z);
        a.w = fmaf(vp, kk.w, a.w);
        hv = fmaf(a.x, qq.x, hv);
        hv = fmaf(a.y, qq.y, hv);
        hv = fmaf(a.z, qq.z, hv);
        hv = fmaf(a.w, qq.w, hv);
        amo[i] = a;
    }
    h_out[(size_t)b * D_MODEL + n * 64 + lane] = hv * rv;
}

// ---------------------------------------------------------------------------
extern "C" void kernel_launch(void* const* d_in, const int* in_sizes, int n_in,
                              void* d_out, int out_size, void* d_ws, size_t ws_size,
                              hipStream_t stream)
{
    const float* x      = (const float*)d_in[0];
    const float* h      = (const float*)d_in[1];
    const float* AM     = (const float*)d_in[2];
    const float* Wqkv_w = (const float*)d_in[3];
    const float* Wqkv_b = (const float*)d_in[4];
    const float* Ww_w   = (const float*)d_in[5];
    const float* Ww_b   = (const float*)d_in[6];
    const float* Wr_w   = (const float*)d_in[7];
    const float* Wr_b   = (const float*)d_in[8];

    float* out    = (float*)d_out;
    float* h_out  = out;                               // 1024*1024
    float* am_out = out + (size_t)B_SZ * D_MODEL;      // 1024*16*64*64

    float* ws    = (float*)d_ws;
    float* qkv   = ws;                                  // 1024*3072
    float* w_arr = ws + (size_t)B_SZ * N_QKV;           // 1024*16
    float* r_arr = w_arr + (size_t)B_SZ * NHEAD;        // 1024*16

    dim3 g1(N_QKV / 128, B_SZ / 64);
    gemm_qkv_kernel<<<g1, dim3(256), 0, stream>>>(x, h, Wqkv_w, Wqkv_b, qkv);
    gemm_wr_kernel<<<dim3(B_SZ), dim3(256), 0, stream>>>(x, h, Ww_w, Ww_b, Wr_w, Wr_b, w_arr, r_arr);
    am_update_kernel<<<dim3(B_SZ * NHEAD), dim3(64), 0, stream>>>(qkv, AM, w_arr, r_arr, h_out, am_out);
}

// Round 3
// 661.004 us; speedup vs baseline: 1.1219x; 1.1219x over previous
//
#include <hip/hip_runtime.h>
#include <math.h>

#define B_SZ      1024
#define INPUT_DIM 1024
#define D_MODEL   1024
#define NHEAD     16
#define D_HEAD    64
#define K_DIM     2048      // INPUT_DIM + D_MODEL
#define N_QKV     3072

typedef __bf16 bf16x8 __attribute__((ext_vector_type(8)));
typedef float  f32x4  __attribute__((ext_vector_type(4)));

__device__ __forceinline__ unsigned short f2bf(float f) {
    unsigned u = __builtin_bit_cast(unsigned, f);
    u += 0x7fffu + ((u >> 16) & 1u);          // round-to-nearest-even
    return (unsigned short)(u >> 16);
}
__device__ __forceinline__ float bf2f(unsigned short s) {
    unsigned u = ((unsigned)s) << 16;
    return __builtin_bit_cast(float, u);
}
__device__ __forceinline__ uint4 pack8(const unsigned short* s) {
    uint4 r;
    r.x = s[0] | ((unsigned)s[1] << 16);
    r.y = s[2] | ((unsigned)s[3] << 16);
    r.z = s[4] | ((unsigned)s[5] << 16);
    r.w = s[6] | ((unsigned)s[7] << 16);
    return r;
}

// ---------------------------------------------------------------------------
// conv_a: A = concat(x,h) (1024 x 2048 fp32) -> Ahi, Alo (bf16, row-major M x K)
// one block per row, 256 threads x 8 elems
// ---------------------------------------------------------------------------
__global__ __launch_bounds__(256) void conv_a_kernel(
    const float* __restrict__ x, const float* __restrict__ h,
    unsigned short* __restrict__ Ahi, unsigned short* __restrict__ Alo)
{
    const int m = blockIdx.x;
    const int t = threadIdx.x;
    const float* src = (t < 128) ? (x + (size_t)m * INPUT_DIM + t * 8)
                                 : (h + (size_t)m * D_MODEL + t * 8 - INPUT_DIM);
    float4 v0 = ((const float4*)src)[0];
    float4 v1 = ((const float4*)src)[1];
    float f[8] = {v0.x, v0.y, v0.z, v0.w, v1.x, v1.y, v1.z, v1.w};
    unsigned short hi[8], lo[8];
#pragma unroll
    for (int j = 0; j < 8; ++j) {
        hi[j] = f2bf(f[j]);
        lo[j] = f2bf(f[j] - bf2f(hi[j]));
    }
    const size_t off = (size_t)m * K_DIM + t * 8;
    *reinterpret_cast<uint4*>(Ahi + off) = pack8(hi);
    *reinterpret_cast<uint4*>(Alo + off) = pack8(lo);
}

// ---------------------------------------------------------------------------
// conv_b: Wqkv (2048 x 3072 fp32, row-major [k][n]) -> Bthi, Btlo (bf16, N x K
// row-major = transposed). 64x64 tiles via LDS.
// ---------------------------------------------------------------------------
__global__ __launch_bounds__(256) void conv_b_kernel(
    const float* __restrict__ W,
    unsigned short* __restrict__ Bthi, unsigned short* __restrict__ Btlo)
{
    __shared__ float tile[64][65];
    const int n0 = blockIdx.x * 64;
    const int k0 = blockIdx.y * 64;
    const int t  = threadIdx.x;

    const int lrow = t >> 4;          // 0..15
    const int lcol = (t & 15) * 4;
#pragma unroll
    for (int p = 0; p < 4; ++p) {
        const int r = p * 16 + lrow;
        float4 v = *reinterpret_cast<const float4*>(W + (size_t)(k0 + r) * N_QKV + n0 + lcol);
        tile[r][lcol + 0] = v.x;
        tile[r][lcol + 1] = v.y;
        tile[r][lcol + 2] = v.z;
        tile[r][lcol + 3] = v.w;
    }
    __syncthreads();

    const int nl = t >> 2;            // 0..63
    const int kc = (t & 3) * 16;      // 0,16,32,48
    unsigned short hi[16], lo[16];
#pragma unroll
    for (int i = 0; i < 16; ++i) {
        float f = tile[kc + i][nl];
        hi[i] = f2bf(f);
        lo[i] = f2bf(f - bf2f(hi[i]));
    }
    const size_t off = (size_t)(n0 + nl) * K_DIM + k0 + kc;
    *reinterpret_cast<uint4*>(Bthi + off)     = pack8(hi);
    *reinterpret_cast<uint4*>(Bthi + off + 8) = pack8(hi + 8);
    *reinterpret_cast<uint4*>(Btlo + off)     = pack8(lo);
    *reinterpret_cast<uint4*>(Btlo + off + 8) = pack8(lo + 8);
}

// ---------------------------------------------------------------------------
// gemm_qkv_mfma: C = A*B + bias via bf16 hi/lo split (3 MFMA per product).
// BM=BN=128, BK=64, 256 threads (4 waves, 2x2), wave tile 64x64 (4x4 frags of
// 16x16x32). LDS XOR-chunk swizzle: chunk slot = chunk ^ (row&7).
// grid (N/128=24, M/128=8)
// ---------------------------------------------------------------------------
__global__ __launch_bounds__(256) void gemm_qkv_mfma(
    const unsigned short* __restrict__ Ahi, const unsigned short* __restrict__ Alo,
    const unsigned short* __restrict__ Bthi, const unsigned short* __restrict__ Btlo,
    const float* __restrict__ bias, float* __restrict__ out)
{
    __shared__ unsigned short sAh[128 * 64];
    __shared__ unsigned short sAl[128 * 64];
    __shared__ unsigned short sBh[128 * 64];
    __shared__ unsigned short sBl[128 * 64];

    const int t    = threadIdx.x;
    const int lane = t & 63;
    const int wid  = t >> 6;
    const int wm   = wid >> 1;        // 0..1
    const int wn   = wid & 1;         // 0..1
    const int m0   = blockIdx.y * 128;
    const int n0   = blockIdx.x * 128;

    f32x4 acc[4][4];
#pragma unroll
    for (int i = 0; i < 4; ++i)
#pragma unroll
        for (int j = 0; j < 4; ++j) acc[i][j] = (f32x4){0.f, 0.f, 0.f, 0.f};

    for (int kt = 0; kt < K_DIM; kt += 64) {
        uint4 ra[4], rb[4], rc[4], rd[4];
#pragma unroll
        for (int p = 0; p < 4; ++p) {
            const int pi = p * 256 + t;
            const int R  = pi >> 3;
            const int cs = pi & 7;
            const int cl = cs ^ (R & 7);      // logical chunk living in slot cs
            const size_t ga = (size_t)(m0 + R) * K_DIM + kt + cl * 8;
            const size_t gb = (size_t)(n0 + R) * K_DIM + kt + cl * 8;
            ra[p] = *reinterpret_cast<const uint4*>(Ahi  + ga);
            rb[p] = *reinterpret_cast<const uint4*>(Alo  + ga);
            rc[p] = *reinterpret_cast<const uint4*>(Bthi + gb);
            rd[p] = *reinterpret_cast<const uint4*>(Btlo + gb);
        }
        __syncthreads();          // previous tile fully consumed
#pragma unroll
        for (int p = 0; p < 4; ++p) {
            const int pi = p * 256 + t;
            *reinterpret_cast<uint4*>(&sAh[pi * 8]) = ra[p];
            *reinterpret_cast<uint4*>(&sAl[pi * 8]) = rb[p];
            *reinterpret_cast<uint4*>(&sBh[pi * 8]) = rc[p];
            *reinterpret_cast<uint4*>(&sBl[pi * 8]) = rd[p];
        }
        __syncthreads();

#pragma unroll
        for (int kk = 0; kk < 2; ++kk) {
            bf16x8 ah[4], al[4], bh[4], bl[4];
#pragma unroll
            for (int i = 0; i < 4; ++i) {
                const int RA = wm * 64 + i * 16 + (lane & 15);
                const int ca = (kk * 4 + (lane >> 4)) ^ (RA & 7);
                ah[i] = *reinterpret_cast<const bf16x8*>(&sAh[RA * 64 + ca * 8]);
                al[i] = *reinterpret_cast<const bf16x8*>(&sAl[RA * 64 + ca * 8]);
                const int RB = wn * 64 + i * 16 + (lane & 15);
                const int cb = (kk * 4 + (lane >> 4)) ^ (RB & 7);
                bh[i] = *reinterpret_cast<const bf16x8*>(&sBh[RB * 64 + cb * 8]);
                bl[i] = *reinterpret_cast<const bf16x8*>(&sBl[RB * 64 + cb * 8]);
            }
#pragma unroll
            for (int mi = 0; mi < 4; ++mi)
#pragma unroll
                for (int ni = 0; ni < 4; ++ni) {
                    acc[mi][ni] = __builtin_amdgcn_mfma_f32_16x16x32_bf16(ah[mi], bh[ni], acc[mi][ni], 0, 0, 0);
                    acc[mi][ni] = __builtin_amdgcn_mfma_f32_16x16x32_bf16(ah[mi], bl[ni], acc[mi][ni], 0, 0, 0);
                    acc[mi][ni] = __builtin_amdgcn_mfma_f32_16x16x32_bf16(al[mi], bh[ni], acc[mi][ni], 0, 0, 0);
                }
        }
    }

    // epilogue: + bias, fp32 store.  C/D layout: col = lane&15, row = (lane>>4)*4 + r
#pragma unroll
    for (int mi = 0; mi < 4; ++mi)
#pragma unroll
        for (int ni = 0; ni < 4; ++ni) {
            const int col = n0 + wn * 64 + ni * 16 + (lane & 15);
            const float bv = bias[col];
#pragma unroll
            for (int r = 0; r < 4; ++r) {
                const int row = m0 + wm * 64 + mi * 16 + (lane >> 4) * 4 + r;
                out[(size_t)row * N_QKV + col] = acc[mi][ni][r] + bv;
            }
        }
}

// ---------------------------------------------------------------------------
// gemm_wr (unchanged from passing baseline)
// ---------------------------------------------------------------------------
__global__ __launch_bounds__(256) void gemm_wr_kernel(
    const float* __restrict__ x, const float* __restrict__ h,
    const float* __restrict__ Ww, const float* __restrict__ Wwb,
    const float* __restrict__ Wr, const float* __restrict__ Wrb,
    float* __restrict__ w_out, float* __restrict__ r_out)
{
    const int b     = blockIdx.x;
    const int tid   = threadIdx.x;
    const int j     = tid & 31;
    const int slice = tid >> 5;
    const int col   = j & 15;
    const float* Wm = (j < 16) ? Ww : Wr;

    const int k0 = slice * 256;
    const float* src = (k0 < INPUT_DIM) ? (x + (size_t)b * INPUT_DIM + k0)
                                        : (h + (size_t)b * D_MODEL + (k0 - INPUT_DIM));
    float acc = 0.f;
#pragma unroll 8
    for (int i = 0; i < 256; ++i)
        acc = fmaf(src[i], Wm[(size_t)(k0 + i) * NHEAD + col], acc);

    __shared__ float red[8][32];
    red[slice][j] = acc;
    __syncthreads();
    if (tid < 32) {
        float s = 0.f;
#pragma unroll
        for (int i = 0; i < 8; ++i) s += red[i][tid];
        const int cc = tid & 15;
        if (tid < 16) {
            s += Wwb[cc];
            w_out[(size_t)b * NHEAD + cc] = 1.f / (1.f + expf(-s));
        } else {
            s += Wrb[cc];
            r_out[(size_t)b * NHEAD + cc] = 1.f / (1.f + expf(-s));
        }
    }
}

// ---------------------------------------------------------------------------
// am_update: 4 waves/block, one (b,n) per wave, grid 4096.
// Coalesced column-chunk ownership: lane owns cols 4c..4c+3 (c = lane&15) of
// rows v = 4i + g (g = lane>>4, i = 0..15). All AM traffic is contiguous
// 1KB/wave-instruction. Row reductions via 16-lane shfl_xor butterflies.
// ---------------------------------------------------------------------------
__global__ __launch_bounds__(256) void am_update_kernel(
    const float* __restrict__ qkv, const float* __restrict__ AM,
    const float* __restrict__ w_arr, const float* __restrict__ r_arr,
    float* __restrict__ h_out, float* __restrict__ am_out)
{
    const int wid  = threadIdx.x >> 6;
    const int lane = threadIdx.x & 63;
    const int bn   = blockIdx.x * 4 + wid;
    const int b    = bn >> 4;
    const int n    = bn & 15;

    const float* row = qkv + (size_t)b * N_QKV;
    float qv = row[             n * 64 + lane];
    float kv = row[D_MODEL    + n * 64 + lane];
    float vv = row[2 * D_MODEL + n * 64 + lane];

    float qs = qv * qv, ks = kv * kv;
#pragma unroll
    for (int off = 32; off > 0; off >>= 1) {
        qs += __shfl_xor(qs, off);
        ks += __shfl_xor(ks, off);
    }
    const float qn = qv / fmaxf(sqrtf(qs), 1e-12f);
    const float kn = kv / fmaxf(sqrtf(ks), 1e-12f);

    const int c = lane & 15;      // column chunk
    const int g = lane >> 4;      // row phase
    float kk[4], qq[4];
#pragma unroll
    for (int j = 0; j < 4; ++j) {
        kk[j] = __shfl(kn, 4 * c + j);
        qq[j] = __shfl(qn, 4 * c + j);
    }

    // AM load: flat float4 index fi = i*64 + lane -> row 4i+g, cols 4c..4c+3
    const float4* amp = reinterpret_cast<const float4*>(AM + (size_t)bn * 4096);
    float4 am[16];
#pragma unroll
    for (int i = 0; i < 16; ++i) am[i] = amp[i * 64 + lane];

    // v_r partials over owned columns
    float vr[16];
#pragma unroll
    for (int i = 0; i < 16; ++i)
        vr[i] = am[i].x * kk[0] + am[i].y * kk[1] + am[i].z * kk[2] + am[i].w * kk[3];
    // reduce across the 16 lanes sharing g
#pragma unroll
    for (int off = 1; off < 16; off <<= 1)
#pragma unroll
        for (int i = 0; i < 16; ++i) vr[i] += __shfl_xor(vr[i], off);

    const float wv = w_arr[bn];
    const float rv = r_arr[bn];

    float vel[16];
#pragma unroll
    for (int i = 0; i < 16; ++i) vel[i] = __shfl(vv, 4 * i + g);

    float4* amo = reinterpret_cast<float4*>(am_out + (size_t)bn * 4096);
    float hp[16];
#pragma unroll
    for (int i = 0; i < 16; ++i) {
        const float vp = wv * (vel[i] - vr[i]);
        float4 a = am[i];
        a.x = fmaf(vp, kk[0], a.x);
        a.y = fmaf(vp, kk[1], a.y);
        a.z = fmaf(vp, kk[2], a.z);
        a.w = fmaf(vp, kk[3], a.w);
        hp[i] = a.x * qq[0] + a.y * qq[1] + a.z * qq[2] + a.w * qq[3];
        amo[i * 64 + lane] = a;
    }
#pragma unroll
    for (int off = 1; off < 16; off <<= 1)
#pragma unroll
        for (int i = 0; i < 16; ++i) hp[i] += __shfl_xor(hp[i], off);

    // lane (g,c) writes row 4c+g using hp[c] (static-index selection, no scratch)
    float hsel = 0.f;
#pragma unroll
    for (int i = 0; i < 16; ++i) if (c == i) hsel = hp[i];
    h_out[(size_t)b * D_MODEL + n * 64 + 4 * c + g] = hsel * rv;
}

// ---------------------------------------------------------------------------
extern "C" void kernel_launch(void* const* d_in, const int* in_sizes, int n_in,
                              void* d_out, int out_size, void* d_ws, size_t ws_size,
                              hipStream_t stream)
{
    const float* x      = (const float*)d_in[0];
    const float* h      = (const float*)d_in[1];
    const float* AM     = (const float*)d_in[2];
    const float* Wqkv_w = (const float*)d_in[3];
    const float* Wqkv_b = (const float*)d_in[4];
    const float* Ww_w   = (const float*)d_in[5];
    const float* Ww_b   = (const float*)d_in[6];
    const float* Wr_w   = (const float*)d_in[7];
    const float* Wr_b   = (const float*)d_in[8];

    float* out    = (float*)d_out;
    float* h_out  = out;
    float* am_out = out + (size_t)B_SZ * D_MODEL;

    float* ws    = (float*)d_ws;
    float* qkv   = ws;                                   // 1024*3072 f32
    float* w_arr = qkv + (size_t)B_SZ * N_QKV;           // 16384
    float* r_arr = w_arr + B_SZ * NHEAD;                 // 16384
    unsigned short* Ahi  = (unsigned short*)(r_arr + B_SZ * NHEAD);
    unsigned short* Alo  = Ahi + (size_t)B_SZ * K_DIM;
    unsigned short* Bthi = Alo + (size_t)B_SZ * K_DIM;
    unsigned short* Btlo = Bthi + (size_t)N_QKV * K_DIM;

    conv_a_kernel<<<dim3(B_SZ), dim3(256), 0, stream>>>(x, h, Ahi, Alo);
    conv_b_kernel<<<dim3(N_QKV / 64, K_DIM / 64), dim3(256), 0, stream>>>(Wqkv_w, Bthi, Btlo);
    gemm_wr_kernel<<<dim3(B_SZ), dim3(256), 0, stream>>>(x, h, Ww_w, Ww_b, Wr_w, Wr_b, w_arr, r_arr);
    gemm_qkv_mfma<<<dim3(N_QKV / 128, B_SZ / 128), dim3(256), 0, stream>>>(Ahi, Alo, Bthi, Btlo, Wqkv_b, qkv);
    am_update_kernel<<<dim3(B_SZ * NHEAD / 4), dim3(256), 0, stream>>>(qkv, AM, w_arr, r_arr, h_out, am_out);
}